// Round 6
// baseline (213.181 us; speedup 1.0000x reference)
//
#include <hip/hip_runtime.h>

typedef _Float16 half2v __attribute__((ext_vector_type(2)));
typedef __fp16 fp16x2 __attribute__((ext_vector_type(2)));
typedef _Float16 half4 __attribute__((ext_vector_type(4)));
typedef _Float16 half8 __attribute__((ext_vector_type(8)));
typedef float floatx4 __attribute__((ext_vector_type(4)));

#define B_   8
#define SE   4096
#define SD   4096
#define D_   128
#define NT   64
#define LDB  136
#define LOG2E 1.44269504f

// async 16B global->LDS: per-lane global address, wave-uniform LDS base (+lane*16 by HW)
__device__ __forceinline__ void cp16_async(const _Float16* g, _Float16* l) {
    __builtin_amdgcn_global_load_lds((const __attribute__((address_space(1))) unsigned int*)g,
                                     (__attribute__((address_space(3))) unsigned int*)l, 16, 0, 0);
}

// ---------- prep 0: W16 = fp16(W), Wlo = fp16(W - W16)  (error split) ----------
__global__ __launch_bounds__(256) void wprep(const float* __restrict__ W,
                                             _Float16* __restrict__ W16,
                                             _Float16* __restrict__ Wlo) {
    int i = blockIdx.x * 256 + threadIdx.x;   // grid 64 -> 16384
    float w = W[i];
    _Float16 hi = (_Float16)w;
    W16[i] = hi;
    Wlo[i] = (_Float16)(w - (float)hi);
}

// ---------- prep 1: k' = fp16(b @ W^T) (error-split MFMA), vT = fp16(b^T) ----------
__global__ __launch_bounds__(256) void kvprep(const float* __restrict__ b,
                                              const _Float16* __restrict__ W16,
                                              const _Float16* __restrict__ Wlo,
                                              _Float16* __restrict__ kp,
                                              _Float16* __restrict__ vT) {
    __shared__ _Float16 bs[64 * LDB];   // 17408 B (reused for k' staging)
    const int bb = blockIdx.y, s0 = blockIdx.x * 64;
    const int tid = threadIdx.x, wave = tid >> 6, lane = tid & 63;
    const int l15 = lane & 15, quad = lane >> 4;

    // phase 1: stage fp16(b tile)
    const float* bg = b + ((size_t)bb * SE + s0) * D_;
    #pragma unroll
    for (int it = 0; it < 4; ++it) {
        int idx = tid + it * 256;
        int row = idx >> 4, seg = idx & 15;
        const float* src = bg + row * D_ + seg * 8;
        float4 a = *(const float4*)src;
        float4 c = *(const float4*)(src + 4);
        half8 hv;
        hv[0] = (_Float16)a.x; hv[1] = (_Float16)a.y; hv[2] = (_Float16)a.z; hv[3] = (_Float16)a.w;
        hv[4] = (_Float16)c.x; hv[5] = (_Float16)c.y; hv[6] = (_Float16)c.z; hv[7] = (_Float16)c.w;
        *(half8*)(bs + row * LDB + seg * 8) = hv;
    }
    __syncthreads();

    // phase 2: k'[s][d] = sum_e b[s][e] W[d][e]
    half8 af[4];
    #pragma unroll
    for (int ks = 0; ks < 4; ++ks)
        af[ks] = *(const half8*)(bs + (wave * 16 + l15) * LDB + ks * 32 + quad * 8);
    floatx4 acc[8];
    #pragma unroll
    for (int nt = 0; nt < 8; ++nt) acc[nt] = (floatx4){0.f, 0.f, 0.f, 0.f};
    #pragma unroll
    for (int ks = 0; ks < 4; ++ks) {
        #pragma unroll
        for (int nt = 0; nt < 8; ++nt) {
            half8 bh = *(const half8*)(W16 + (size_t)(nt * 16 + l15) * 128 + ks * 32 + quad * 8);
            half8 bl = *(const half8*)(Wlo + (size_t)(nt * 16 + l15) * 128 + ks * 32 + quad * 8);
            acc[nt] = __builtin_amdgcn_mfma_f32_16x16x32_f16(af[ks], bh, acc[nt], 0, 0, 0);
            acc[nt] = __builtin_amdgcn_mfma_f32_16x16x32_f16(af[ks], bl, acc[nt], 0, 0, 0);
        }
    }

    // phase 3: vT = fp16(b^T), 8x8 register transpose, half8 coalesced writes
    if (tid < 128) {
        const int sb = tid & 7, dg = tid >> 3;    // s-chunk 0..7, d-group 0..15
        half8 rowv[8];
        #pragma unroll
        for (int j = 0; j < 8; ++j)
            rowv[j] = *(const half8*)(bs + (sb * 8 + j) * LDB + dg * 8);
        #pragma unroll
        for (int r = 0; r < 8; ++r) {
            int d = dg * 8 + r;
            half8 o;
            #pragma unroll
            for (int j = 0; j < 8; ++j) o[j] = rowv[j][r];
            *(half8*)(vT + ((size_t)bb * D_ + d) * SE + s0 + sb * 8) = o;
        }
    }
    __syncthreads();

    // phase 4: k' C-frags -> bs (overwrite), then coalesced row-major writeout
    #pragma unroll
    for (int nt = 0; nt < 8; ++nt)
        #pragma unroll
        for (int r = 0; r < 4; ++r)
            bs[(wave * 16 + quad * 4 + r) * LDB + nt * 16 + l15] = (_Float16)acc[nt][r];
    __syncthreads();
    _Float16* kg = kp + ((size_t)bb * SE + s0) * D_;
    {
        const int row = tid >> 2;
        #pragma unroll
        for (int it = 0; it < 4; ++it) {
            int ch = (tid & 3) + it * 4;          // 16 chunks of 8 halves per row
            half8 v = *(const half8*)(bs + row * LDB + ch * 8);
            *(half8*)(kg + row * D_ + ch * 8) = v;
        }
    }
}

// ---------- fused flash attention ----------
// Double-buffered LDS via global_load_lds (XOR-swizzled chunk images), one
// barrier per tile. S^T = K' Q^T (16x16x32), P register-chained into
// O += P V (16x16x16). All LDS read addresses hoisted: per tile only a
// buffer-select cndmask; ds_reads use immediate offsets.
__global__ __launch_bounds__(256, 2) void flash(const float* __restrict__ h,
                                                const _Float16* __restrict__ k,
                                                const _Float16* __restrict__ vT,
                                                float* __restrict__ out) {
    __shared__ _Float16 KV[2][16384];   // per buf: Ks image 8192 halves + Vts image 8192

    const int bb   = blockIdx.y;
    const int q0   = blockIdx.x * 64;
    const int tid  = threadIdx.x;
    const int wave = tid >> 6;
    const int lane = tid & 63;
    const int l15  = lane & 15;
    const int quad = lane >> 4;

    const _Float16* kbase = k + (size_t)bb * SE * D_;
    const _Float16* vbase = vT + (size_t)bb * D_ * SE;

    // per-lane gather offsets (within-tile, halves); XOR swizzle on the global side
    int koff[4], voff[4];
    #pragma unroll
    for (int j = 0; j < 4; ++j) {
        int i = (wave * 4 + j) * 64 + lane;       // linear 16B chunk index in tile image
        int kr = i >> 4, kpp = i & 15;
        koff[j] = kr * D_ + (kpp ^ (kr & 15)) * 8;
        int vr = i >> 3, vpp = i & 7;
        voff[j] = vr * SE + (vpp ^ (vr & 7)) * 8;
    }

    // hoisted LDS read bases (per buffer); inner loop adds compile-time offsets only
    const _Float16* kA0[4]; const _Float16* kA1[4];
    const _Float16* vB0[4]; const _Float16* vB1[4];
    #pragma unroll
    for (int ks = 0; ks < 4; ++ks) {
        int o = l15 * 128 + (((ks * 4 + quad) ^ l15) * 8);
        kA0[ks] = &KV[0][o]; kA1[ks] = &KV[1][o];
    }
    #pragma unroll
    for (int st = 0; st < 4; ++st) {
        int o = 8192 + l15 * 64 + (((st * 2 + (quad >> 1)) ^ (l15 & 7)) * 8) + (quad & 1) * 4;
        vB0[st] = &KV[0][o]; vB1[st] = &KV[1][o];
    }

    // issue tile 0 DMA
    {
        _Float16* buf0 = &KV[0][0];
        #pragma unroll
        for (int j = 0; j < 4; ++j) {
            cp16_async(kbase + koff[j], buf0 + (wave * 4 + j) * 512);
            cp16_async(vbase + voff[j], buf0 + 8192 + (wave * 4 + j) * 512);
        }
    }

    // Q = fp16(h * log2e) as B-fragments: B[n=q=l15][k=d=quad*8+j]
    const float* hrow = h + ((size_t)bb * SD + q0 + wave * 16 + l15) * D_;
    half8 qf[4];
    #pragma unroll
    for (int ks = 0; ks < 4; ++ks) {
        float4 a = *(const float4*)(hrow + ks * 32 + quad * 8);
        float4 c = *(const float4*)(hrow + ks * 32 + quad * 8 + 4);
        half8 f;
        f[0] = (_Float16)(a.x * LOG2E); f[1] = (_Float16)(a.y * LOG2E);
        f[2] = (_Float16)(a.z * LOG2E); f[3] = (_Float16)(a.w * LOG2E);
        f[4] = (_Float16)(c.x * LOG2E); f[5] = (_Float16)(c.y * LOG2E);
        f[6] = (_Float16)(c.z * LOG2E); f[7] = (_Float16)(c.w * LOG2E);
        qf[ks] = f;
    }

    floatx4 acc_o[8];
    #pragma unroll
    for (int i = 0; i < 8; ++i) acc_o[i] = (floatx4){0.f, 0.f, 0.f, 0.f};
    float m_q = -1e30f;   // running max (base-2 domain), uniform across quads
    float l_part = 0.f;   // per-lane partial denominator
    const half2v one2 = { (_Float16)1.f, (_Float16)1.f };

    for (int t = 0; t < SE / NT; ++t) {
        __syncthreads();   // vmcnt drain here -> tile t landed for all waves
        if (t + 1 < SE / NT) {   // async DMA for t+1; in flight across this tile's compute
            const _Float16* kt = kbase + (size_t)(t + 1) * (NT * D_);
            const _Float16* vt = vbase + (size_t)(t + 1) * NT;
            _Float16* bufn = &KV[(t + 1) & 1][0];
            #pragma unroll
            for (int j = 0; j < 4; ++j) {
                cp16_async(kt + koff[j], bufn + (wave * 4 + j) * 512);
                cp16_async(vt + voff[j], bufn + 8192 + (wave * 4 + j) * 512);
            }
        }
        const bool odd = (t & 1) != 0;
        const _Float16* kA[4]; const _Float16* vB[4];
        #pragma unroll
        for (int i = 0; i < 4; ++i) { kA[i] = odd ? kA1[i] : kA0[i]; vB[i] = odd ? vB1[i] : vB0[i]; }

        // S^T = K Q^T : C row = s_local = quad*4+r, col = q = l15
        floatx4 accs[4];
        #pragma unroll
        for (int st = 0; st < 4; ++st) accs[st] = (floatx4){0.f, 0.f, 0.f, 0.f};
        #pragma unroll
        for (int ks = 0; ks < 4; ++ks) {
            #pragma unroll
            for (int st = 0; st < 4; ++st) {
                half8 af = *(const half8*)(kA[ks] + st * 2048);   // ds_read_b128 offset:st*4096
                accs[st] = __builtin_amdgcn_mfma_f32_16x16x32_f16(af, qf[ks], accs[st], 0, 0, 0);
            }
        }

        // deferred-rescale online softmax, base-2 (fast path: no cross-lane ops)
        float mx[8];
        #pragma unroll
        for (int i = 0; i < 8; ++i) mx[i] = fmaxf(accs[i >> 1][(i & 1) * 2], accs[i >> 1][(i & 1) * 2 + 1]);
        float m4a = fmaxf(fmaxf(mx[0], mx[1]), fmaxf(mx[2], mx[3]));
        float m4b = fmaxf(fmaxf(mx[4], mx[5]), fmaxf(mx[6], mx[7]));
        float mv16 = fmaxf(m4a, m4b);
        bool cond = mv16 > m_q + 11.5f;
        if (__ballot(cond) != 0ull) {        // rare wave-uniform slow path
            float mv = mv16;
            mv = fmaxf(mv, __shfl_xor(mv, 16, 64));
            mv = fmaxf(mv, __shfl_xor(mv, 32, 64));
            float mnew = fmaxf(m_q, mv);
            float alpha = exp2f(m_q - mnew);
            l_part *= alpha;
            float ab[4];
            #pragma unroll
            for (int r = 0; r < 4; ++r) ab[r] = __shfl(alpha, quad * 4 + r, 64);
            #pragma unroll
            for (int dt = 0; dt < 8; ++dt)
                #pragma unroll
                for (int r = 0; r < 4; ++r) acc_o[dt][r] *= ab[r];
            m_q = mnew;
        }

        // P = 2^(S^T - m); pf[st] IS the PV A-fragment; l via packed dot2
        half4 pf[4];
        #pragma unroll
        for (int st = 0; st < 4; ++st) {
            float p0 = exp2f(accs[st][0] - m_q);
            float p1 = exp2f(accs[st][1] - m_q);
            float p2 = exp2f(accs[st][2] - m_q);
            float p3 = exp2f(accs[st][3] - m_q);
            half2v lo = __builtin_bit_cast(half2v, __builtin_amdgcn_cvt_pkrtz(p0, p1));
            half2v hi = __builtin_bit_cast(half2v, __builtin_amdgcn_cvt_pkrtz(p2, p3));
#if __has_builtin(__builtin_amdgcn_fdot2)
            l_part = __builtin_amdgcn_fdot2(lo, one2, l_part, false);
            l_part = __builtin_amdgcn_fdot2(hi, one2, l_part, false);
#else
            l_part += p0 + p1 + p2 + p3;
#endif
            half4 pv; pv[0] = lo[0]; pv[1] = lo[1]; pv[2] = hi[0]; pv[3] = hi[1];
            pf[st] = pv;
        }

        // O += P V : B-frag from swizzled V image; ds_read_b64 offset:dt*2048
        #pragma unroll
        for (int st = 0; st < 4; ++st) {
            #pragma unroll
            for (int dt = 0; dt < 8; ++dt) {
                half4 vf = *(const half4*)(vB[st] + dt * 1024);
                acc_o[dt] = __builtin_amdgcn_mfma_f32_16x16x16f16(pf[st], vf, acc_o[dt], 0, 0, 0);
            }
        }
    }

    // final denominator reduction + epilogue
    l_part += __shfl_xor(l_part, 16, 64);
    l_part += __shfl_xor(l_part, 32, 64);
    float linv = 1.f / l_part;
    float lb[4];
    #pragma unroll
    for (int r = 0; r < 4; ++r) lb[r] = __shfl(linv, quad * 4 + r, 64);
    float* orow = out + ((size_t)bb * SD + q0 + wave * 16) * D_;
    #pragma unroll
    for (int dt = 0; dt < 8; ++dt)
        #pragma unroll
        for (int r = 0; r < 4; ++r)
            orow[(size_t)(quad * 4 + r) * D_ + dt * 16 + l15] = acc_o[dt][r] * lb[r];
}

extern "C" void kernel_launch(void* const* d_in, const int* in_sizes, int n_in,
                              void* d_out, int out_size, void* d_ws, size_t ws_size,
                              hipStream_t stream) {
    const float* b = (const float*)d_in[0];   // [B, SE, D]
    const float* h = (const float*)d_in[1];   // [B, SD, D]
    const float* W = (const float*)d_in[2];   // [D, D]
    float* out = (float*)d_out;               // [B, SD, D] fp32

    _Float16* W16 = (_Float16*)d_ws;                       // 32 KB
    _Float16* Wlo = W16 + 128 * 128;                       // 32 KB
    _Float16* kp  = Wlo + 128 * 128;                       // [B, SE, D] fp16
    _Float16* vT  = kp + (size_t)B_ * SE * D_;             // [B, D, SE] fp16

    wprep<<<64, 256, 0, stream>>>(W, W16, Wlo);
    kvprep<<<dim3(SE / 64, B_), 256, 0, stream>>>(b, W16, Wlo, kp, vT);
    flash<<<dim3(SD / 64, B_), 256, 0, stream>>>(h, kp, vT, out);
}